// Round 3
// baseline (554.235 us; speedup 1.0000x reference)
//
#include <hip/hip_runtime.h>
#include <math.h>

#define B_SZ 8192
#define KD   256
#define KE   768          // extended K: [hi | lo | hi] x [hi | hi | lo]
#define NCLS 32
#define INV_T 10.0f

typedef __attribute__((ext_vector_type(8))) short short8;
typedef __attribute__((ext_vector_type(4))) float f32x4;

static __device__ __forceinline__ unsigned short f2bf(float f) {
    unsigned u = __float_as_uint(f);
    unsigned r = (u + 0x7FFF + ((u >> 16) & 1)) >> 16;   // RNE
    return (unsigned short)r;
}

// ---------------- kernel 1: normalize rows, emit extended bf16 operands ----------------
// Aext[row] = [hi(256) | lo(256) | hi(256)], Bext[row] = [hi | hi | lo]
// => Aext . Bext^T over K=768 == Ahi.Bhi + Alo.Bhi + Ahi.Blo  (drops lo.lo ~ 2^-16 rel)
__global__ void prep_kernel(const float* __restrict__ feat,
                            unsigned short* __restrict__ Aext,
                            unsigned short* __restrict__ Bext) {
    int row  = blockIdx.x * 4 + (threadIdx.x >> 6);
    int lane = threadIdx.x & 63;
    const float4 v = ((const float4*)(feat + (size_t)row * KD))[lane];
    float s = v.x * v.x + v.y * v.y + v.z * v.z + v.w * v.w;
    #pragma unroll
    for (int off = 1; off < 64; off <<= 1) s += __shfl_xor(s, off, 64);
    float rn = rsqrtf(s);
    float fn[4] = {v.x * rn, v.y * rn, v.z * rn, v.w * rn};
    ushort4 hi, lo;
    unsigned short* hp = (unsigned short*)&hi;
    unsigned short* lp = (unsigned short*)&lo;
    #pragma unroll
    for (int e = 0; e < 4; e++) {
        unsigned short h = f2bf(fn[e]);
        float hf = __uint_as_float((unsigned)h << 16);
        hp[e] = h;
        lp[e] = f2bf(fn[e] - hf);
    }
    ushort4* ar = (ushort4*)(Aext + (size_t)row * KE);
    ar[lane] = hi;  ar[lane + 64] = lo;  ar[lane + 128] = hi;
    ushort4* br = (ushort4*)(Bext + (size_t)row * KE);
    br[lane] = hi;  br[lane + 64] = hi;  br[lane + 128] = lo;
}

// ---------------- kernel 2: global per-class counts ----------------
__global__ void count_kernel(const int* __restrict__ labels, int* __restrict__ counts) {
    __shared__ int sc[NCLS];
    int t = threadIdx.x;
    if (t < NCLS) sc[t] = 0;
    __syncthreads();
    for (int i = t; i < B_SZ; i += 256) atomicAdd(&sc[labels[i]], 1);
    __syncthreads();
    if (t < NCLS) counts[t] = sc[t];
}

// ---------------- kernel 3: single-pass K=768 MFMA GEMM + exp + class scatter ----------------
// 1-D grid of 64*nchunk blocks, XCD-swizzled. 128x128 C-tile, 4 waves 2x2, 64x64/wave.
__global__ __launch_bounds__(256) void sim_kernel(
    const unsigned short* __restrict__ Aext, const unsigned short* __restrict__ Bext,
    const int* __restrict__ labels,
    float* __restrict__ pcls, float* __restrict__ ppos, int nchunk)
{
    __shared__ __align__(16) unsigned short sA[128 * 64];  // 16KB
    __shared__ __align__(16) unsigned short sB[128 * 64];  // 16KB
    __shared__ float scls[128][NCLS + 1];
    __shared__ float spos[128];

    const int nblk = 64 * nchunk;
    const int bid  = blockIdx.x;
    const int swz  = (bid & 7) * (nblk >> 3) + (bid >> 3);   // bijective: nblk % 8 == 0
    const int itile = swz / nchunk;
    const int jc    = swz % nchunk;
    const int jtpc  = 64 / nchunk;

    const int t    = threadIdx.x;
    const int wave = t >> 6;
    const int lane = t & 63;
    const int wr   = wave >> 1;
    const int wc   = wave & 1;
    const int l15  = lane & 15;
    const int l4   = lane >> 4;
    const int i0   = itile * 128;

    for (int s = t; s < 128 * (NCLS + 1); s += 256) ((float*)scls)[s] = 0.0f;
    if (t < 128) spos[t] = 0.0f;

    int labi[4][4];
    #pragma unroll
    for (int m = 0; m < 4; m++)
        #pragma unroll
        for (int q = 0; q < 4; q++)
            labi[m][q] = labels[i0 + wr * 64 + m * 16 + l4 * 4 + q];

    const int rL = t >> 3;        // row-within-32 this thread stages
    const int s8 = t & 7;         // physical 16B slot

    #pragma unroll 1
    for (int jt = jc * jtpc; jt < (jc + 1) * jtpc; ++jt) {
        const int j0 = jt * 128;
        f32x4 acc[4][4];
        #pragma unroll
        for (int m = 0; m < 4; m++)
            #pragma unroll
            for (int n = 0; n < 4; n++)
                acc[m][n] = (f32x4){0.f, 0.f, 0.f, 0.f};

        #pragma unroll 1
        for (int kc = 0; kc < KE; kc += 64) {
            __syncthreads();
            #pragma unroll
            for (int a = 0; a < 4; ++a) {
                int r   = a * 32 + rL;
                int ksw = (s8 ^ (r & 7)) * 8;   // pre-swizzled global source (rule #21)
                const unsigned short* gA = Aext + (size_t)(i0 + r) * KE + kc + ksw;
                char* lA = (char*)sA + a * 4096 + wave * 1024;
                __builtin_amdgcn_global_load_lds(
                    (const __attribute__((address_space(1))) void*)gA,
                    (__attribute__((address_space(3))) void*)lA, 16, 0, 0);
                const unsigned short* gB = Bext + (size_t)(j0 + r) * KE + kc + ksw;
                char* lB = (char*)sB + a * 4096 + wave * 1024;
                __builtin_amdgcn_global_load_lds(
                    (const __attribute__((address_space(1))) void*)gB,
                    (__attribute__((address_space(3))) void*)lB, 16, 0, 0);
            }
            __syncthreads();

            #pragma unroll
            for (int kk = 0; kk < 2; ++kk) {
                short8 af[4], bf4[4];
                #pragma unroll
                for (int m = 0; m < 4; ++m) {
                    int r    = wr * 64 + m * 16 + l15;
                    int slog = kk * 4 + l4;
                    af[m] = *(const short8*)&sA[r * 64 + ((slog ^ (r & 7)) * 8)];
                }
                #pragma unroll
                for (int n = 0; n < 4; ++n) {
                    int r    = wc * 64 + n * 16 + l15;
                    int slog = kk * 4 + l4;
                    bf4[n] = *(const short8*)&sB[r * 64 + ((slog ^ (r & 7)) * 8)];
                }
                #pragma unroll
                for (int m = 0; m < 4; ++m)
                    #pragma unroll
                    for (int n = 0; n < 4; ++n)
                        acc[m][n] = __builtin_amdgcn_mfma_f32_16x16x32_bf16(
                            af[m], bf4[n], acc[m][n], 0, 0, 0);
            }
        }

        // epilogue: scale -> exp -> LDS scatter (C: col=lane&15, row=(lane>>4)*4+reg)
        int labj[4];
        #pragma unroll
        for (int n = 0; n < 4; ++n)
            labj[n] = labels[j0 + wc * 64 + n * 16 + l15];
        #pragma unroll
        for (int m = 0; m < 4; ++m) {
            #pragma unroll
            for (int n = 0; n < 4; ++n) {
                const int jg = j0 + wc * 64 + n * 16 + l15;
                #pragma unroll
                for (int q = 0; q < 4; ++q) {
                    const int il = wr * 64 + m * 16 + l4 * 4 + q;
                    const int ig = i0 + il;
                    if (ig == jg) continue;
                    float sim = acc[m][n][q] * INV_T;
                    float e = __expf(sim);
                    atomicAdd(&scls[il][labj[n]], e);
                    if (labj[n] == labi[m][q]) atomicAdd(&spos[il], sim);
                }
            }
        }
    }
    __syncthreads();

    float* pc = pcls + (size_t)swz * 128 * NCLS;
    for (int s = t; s < 128 * NCLS; s += 256) pc[s] = scls[s >> 5][s & 31];
    if (t < 128) ppos[(size_t)swz * 128 + t] = spos[t];
}

// ---------------- kernel 4: per-anchor loss (8 lanes per anchor, coalesced) ----------------
__global__ void reduce_kernel(const float* __restrict__ pcls, const float* __restrict__ ppos,
                              const int* __restrict__ counts, const int* __restrict__ labels,
                              float* __restrict__ loss_i, float* __restrict__ validf, int nchunk) {
    int tid = blockIdx.x * blockDim.x + threadIdx.x;   // B_SZ*8 threads
    int i  = tid >> 3;
    int cq = tid & 7;          // class quad 0..7 -> classes cq*4..cq*4+3
    if (i >= B_SZ) return;
    int itile = i >> 7, ilocal = i & 127;

    f32x4 cs = (f32x4){0.f, 0.f, 0.f, 0.f};
    for (int ch = 0; ch < nchunk; ch++) {
        const float* p = pcls + ((size_t)(itile * nchunk + ch) * 128 + ilocal) * NCLS + cq * 4;
        f32x4 v = *(const f32x4*)p;
        cs = cs + v;
    }
    int labi = labels[i];
    float dpart = 0.0f;
    #pragma unroll
    for (int e = 0; e < 4; e++) {
        int c = cq * 4 + e;
        int cnt = counts[c] - (c == labi ? 1 : 0);
        if (cnt > 0) dpart += cs[e] / (float)cnt;
    }
    #pragma unroll
    for (int off = 1; off < 8; off <<= 1) dpart += __shfl_xor(dpart, off, 64);

    if (cq == 0) {
        float psum = 0.0f;
        for (int ch = 0; ch < nchunk; ch++)
            psum += ppos[(size_t)(itile * nchunk + ch) * 128 + ilocal];
        int P = counts[labi] - 1;
        bool valid = P > 0;
        float li = 0.0f;
        if (valid) li = logf(fmaxf(dpart, 1e-30f)) - psum / (float)max(P, 1);
        loss_i[i] = li;
        validf[i] = valid ? 1.0f : 0.0f;
    }
}

// ---------------- kernel 5: deterministic final reduction ----------------
__global__ void final_kernel(const float* __restrict__ loss_i, const float* __restrict__ validf,
                             float* __restrict__ out) {
    __shared__ float ssum[256];
    __shared__ float scnt[256];
    int t = threadIdx.x;
    float s = 0.0f, c = 0.0f;
    for (int i = t; i < B_SZ; i += 256) { s += loss_i[i]; c += validf[i]; }
    ssum[t] = s; scnt[t] = c;
    __syncthreads();
    #pragma unroll
    for (int off = 128; off > 0; off >>= 1) {
        if (t < off) { ssum[t] += ssum[t + off]; scnt[t] += scnt[t + off]; }
        __syncthreads();
    }
    if (t == 0) out[0] = (scnt[0] > 0.0f) ? ssum[0] / scnt[0] : 0.0f;
}

// ---------------- launch ----------------
extern "C" void kernel_launch(void* const* d_in, const int* in_sizes, int n_in,
                              void* d_out, int out_size, void* d_ws, size_t ws_size,
                              hipStream_t stream) {
    const float* feat   = (const float*)d_in[0];
    const int*   labels = (const int*)d_in[1];
    float*       out    = (float*)d_out;

    char* ws = (char*)d_ws;
    size_t off = 0;
    auto alloc = [&](size_t bytes) -> void* {
        void* p = ws + off;
        off = (off + bytes + 255) & ~(size_t)255;
        return p;
    };

    unsigned short* Aext = (unsigned short*)alloc((size_t)B_SZ * KE * 2);
    unsigned short* Bext = (unsigned short*)alloc((size_t)B_SZ * KE * 2);
    int*   counts = (int*)alloc((size_t)NCLS * 4);
    float* loss_i = (float*)alloc((size_t)B_SZ * 4);
    float* validf = (float*)alloc((size_t)B_SZ * 4);

    int nchunk = 64;   // j-chunks; grid = 64*nchunk blocks
    while (nchunk > 1 &&
           off + (size_t)64 * nchunk * 128 * 4 + (size_t)64 * nchunk * 128 * NCLS * 4 + 4096 > ws_size)
        nchunk >>= 1;
    float* ppos = (float*)alloc((size_t)64 * nchunk * 128 * 4);
    float* pcls = (float*)alloc((size_t)64 * nchunk * 128 * NCLS * 4);

    prep_kernel<<<B_SZ / 4, 256, 0, stream>>>(feat, Aext, Bext);
    count_kernel<<<1, 256, 0, stream>>>(labels, counts);
    sim_kernel<<<64 * nchunk, 256, 0, stream>>>(Aext, Bext, labels, pcls, ppos, nchunk);
    reduce_kernel<<<B_SZ * 8 / 256, 256, 0, stream>>>(pcls, ppos, counts, labels, loss_i, validf, nchunk);
    final_kernel<<<1, 256, 0, stream>>>(loss_i, validf, out);
}

// Round 4
// 260.223 us; speedup vs baseline: 2.1298x; 2.1298x over previous
//
#include <hip/hip_runtime.h>
#include <math.h>

#define B_SZ 8192
#define KD   256
#define KE   768          // extended K: [hi | lo | hi] x [hi | hi | lo]
#define NCLS 32
#define INV_T 10.0f
#define NCHUNK 16         // j-chunks; grid = 64*NCHUNK blocks
#define JTPC  (64 / NCHUNK)
#define NKS   (KE / 64)   // 12 K-steps per j-tile

typedef __attribute__((ext_vector_type(8))) short short8;
typedef __attribute__((ext_vector_type(4))) float f32x4;

static __device__ __forceinline__ unsigned short f2bf(float f) {
    unsigned u = __float_as_uint(f);
    return (unsigned short)((u + 0x7FFF + ((u >> 16) & 1)) >> 16);   // RNE
}
static __device__ __forceinline__ float bf2f(unsigned short h) {
    return __uint_as_float((unsigned)h << 16);
}

// ---------------- kernel 1: normalize rows, emit extended bf16 operands ----------------
__global__ void prep_kernel(const float* __restrict__ feat,
                            unsigned short* __restrict__ Aext,
                            unsigned short* __restrict__ Bext) {
    int row  = blockIdx.x * 4 + (threadIdx.x >> 6);
    int lane = threadIdx.x & 63;
    const float4 v = ((const float4*)(feat + (size_t)row * KD))[lane];
    float s = v.x * v.x + v.y * v.y + v.z * v.z + v.w * v.w;
    #pragma unroll
    for (int off = 1; off < 64; off <<= 1) s += __shfl_xor(s, off, 64);
    float rn = rsqrtf(s);
    float fn[4] = {v.x * rn, v.y * rn, v.z * rn, v.w * rn};
    ushort4 hi, lo;
    unsigned short* hp = (unsigned short*)&hi;
    unsigned short* lp = (unsigned short*)&lo;
    #pragma unroll
    for (int e = 0; e < 4; e++) {
        unsigned short h = f2bf(fn[e]);
        hp[e] = h;
        lp[e] = f2bf(fn[e] - bf2f(h));
    }
    ushort4* ar = (ushort4*)(Aext + (size_t)row * KE);
    ar[lane] = hi;  ar[lane + 64] = lo;  ar[lane + 128] = hi;
    ushort4* br = (ushort4*)(Bext + (size_t)row * KE);
    br[lane] = hi;  br[lane + 64] = hi;  br[lane + 128] = lo;
}

// ---------------- kernel 2: global per-class counts ----------------
__global__ void count_kernel(const int* __restrict__ labels, int* __restrict__ counts) {
    __shared__ int sc[NCLS];
    int t = threadIdx.x;
    if (t < NCLS) sc[t] = 0;
    __syncthreads();
    for (int i = t; i < B_SZ; i += 256) atomicAdd(&sc[labels[i]], 1);
    __syncthreads();
    if (t < NCLS) counts[t] = sc[t];
}

// ---------------- kernel 3: pipelined MFMA sim-GEMM + MFMA class reduction ----------------
// 128x128 C-tile, 4 waves 2x2 (64x64/wave). Swapped MFMA: acc element q holds
// E[i = wr*64+m*16+l15][j = wc*64+n*16+l4*4+q]  (j lane-local along q -> packable).
__global__ __launch_bounds__(256) void sim_kernel(
    const unsigned short* __restrict__ Aext, const unsigned short* __restrict__ Bext,
    const int* __restrict__ labels,
    float* __restrict__ pcls, float* __restrict__ ppos)
{
    __shared__ __align__(16) unsigned short sbuf[2][2][128 * 64];  // 64KB dbuf [buf][A/B]
    __shared__ int   slab[128];
    __shared__ float spos[128];

    const int bid = blockIdx.x;
    const int swz = (bid & 7) * ((64 * NCHUNK) >> 3) + (bid >> 3);  // bijective XCD swizzle
    const int itile = swz / NCHUNK;
    const int jc    = swz % NCHUNK;
    const int i0    = itile * 128;

    const int t    = threadIdx.x;
    const int wave = t >> 6;
    const int lane = t & 63;
    const int wr   = wave >> 1;
    const int wc   = wave & 1;
    const int l15  = lane & 15;
    const int l4   = lane >> 4;
    const int rL   = t >> 3;
    const int s8   = t & 7;

    if (t < 128) spos[t] = 0.0f;

    int labi[4];
    #pragma unroll
    for (int m = 0; m < 4; m++) labi[m] = labels[i0 + wr * 64 + m * 16 + l15];

    auto STAGE = [&](int buf, int j0s, int kc) {
        #pragma unroll
        for (int a = 0; a < 4; ++a) {
            int r   = a * 32 + rL;
            int ksw = (s8 ^ (r & 7)) * 8;     // pre-swizzled global source (rule #21)
            const unsigned short* gA = Aext + (size_t)(i0 + r) * KE + kc + ksw;
            char* lA = (char*)&sbuf[buf][0][0] + a * 4096 + wave * 1024;
            __builtin_amdgcn_global_load_lds(
                (const __attribute__((address_space(1))) void*)gA,
                (__attribute__((address_space(3))) void*)lA, 16, 0, 0);
            const unsigned short* gB = Bext + (size_t)(j0s + r) * KE + kc + ksw;
            char* lB = (char*)&sbuf[buf][1][0] + a * 4096 + wave * 1024;
            __builtin_amdgcn_global_load_lds(
                (const __attribute__((address_space(1))) void*)gB,
                (__attribute__((address_space(3))) void*)lB, 16, 0, 0);
        }
    };

    f32x4 acc_cs[4][2];   // persistent class sums: [m][cb], i=(l4,q), c=cb*16+l15
    #pragma unroll
    for (int m = 0; m < 4; m++)
        #pragma unroll
        for (int cb = 0; cb < 2; cb++)
            acc_cs[m][cb] = (f32x4){0.f, 0.f, 0.f, 0.f};

    STAGE(0, jc * JTPC * 128, 0);
    __syncthreads();

    #pragma unroll 1
    for (int jt = jc * JTPC; jt < (jc + 1) * JTPC; ++jt) {
        const int j0 = jt * 128;
        if (t < 128) slab[t] = labels[j0 + t];

        f32x4 acc[4][4];
        #pragma unroll
        for (int m = 0; m < 4; m++)
            #pragma unroll
            for (int n = 0; n < 4; n++)
                acc[m][n] = (f32x4){0.f, 0.f, 0.f, 0.f};

        // ---- 2-phase pipelined K-loop: stage next BEFORE computing current ----
        #pragma unroll 2
        for (int ks = 0; ks < NKS; ++ks) {
            if (ks < NKS - 1) STAGE((ks + 1) & 1, j0, (ks + 1) * 64);
            const unsigned short* sA = &sbuf[ks & 1][0][0];
            const unsigned short* sB = &sbuf[ks & 1][1][0];
            #pragma unroll
            for (int kk = 0; kk < 2; ++kk) {
                short8 af[4], bf4[4];
                #pragma unroll
                for (int m = 0; m < 4; ++m) {
                    int r = wr * 64 + m * 16 + l15;
                    int slog = kk * 4 + l4;
                    af[m] = *(const short8*)&sA[r * 64 + ((slog ^ (r & 7)) * 8)];
                }
                #pragma unroll
                for (int n = 0; n < 4; ++n) {
                    int r = wc * 64 + n * 16 + l15;
                    int slog = kk * 4 + l4;
                    bf4[n] = *(const short8*)&sB[r * 64 + ((slog ^ (r & 7)) * 8)];
                }
                // swapped: A-operand = bf4 (j-rows), B = af (i-cols) -> q indexes j
                #pragma unroll
                for (int m = 0; m < 4; ++m)
                    #pragma unroll
                    for (int n = 0; n < 4; ++n)
                        acc[m][n] = __builtin_amdgcn_mfma_f32_16x16x32_bf16(
                            bf4[n], af[m], acc[m][n], 0, 0, 0);
            }
            __syncthreads();   // drains this step's stage; syncs buffers
        }

        // ---- epilogue (buf[1] dead -> reuse as sE; prefetch next j-tile into buf[0]) ----
        if (jt + 1 < (jc + 1) * JTPC) STAGE(0, (jt + 1) * 128, 0);

        // sim -> spos atomics (rare) + E=exp in place of acc
        #pragma unroll
        for (int m = 0; m < 4; m++) {
            const int ig = i0 + wr * 64 + m * 16 + l15;
            #pragma unroll
            for (int n = 0; n < 4; n++) {
                const int jb = wc * 64 + n * 16 + l4 * 4;
                int4 lj = *(const int4*)&slab[jb];
                const int* ljp = (const int*)&lj;
                #pragma unroll
                for (int q = 0; q < 4; q++) {
                    const int jg = j0 + jb + q;
                    float sim = acc[m][n][q] * INV_T;
                    bool self = (ig == jg);
                    if (!self && ljp[q] == labi[m])
                        atomicAdd(&spos[wr * 64 + m * 16 + l15], sim);
                    acc[m][n][q] = self ? 0.0f : __expf(sim);
                }
            }
        }

        // one-hot B-fragments (per wave: its own 64-j half = k-blocks {2wc, 2wc+1})
        short8 hf[2][2];
        #pragma unroll
        for (int kk = 0; kk < 2; kk++) {
            const int jb = (wc * 2 + kk) * 32 + l4 * 8;
            int4 lv0 = *(const int4*)&slab[jb];
            int4 lv1 = *(const int4*)&slab[jb + 4];
            int lv[8] = {lv0.x, lv0.y, lv0.z, lv0.w, lv1.x, lv1.y, lv1.z, lv1.w};
            #pragma unroll
            for (int cb = 0; cb < 2; cb++) {
                short8 h;
                #pragma unroll
                for (int e = 0; e < 8; e++)
                    h[e] = (lv[e] == cb * 16 + l15) ? (short)0x3F80 : (short)0;
                hf[kk][cb] = h;
            }
        }

        char* sE = (char*)&sbuf[1][0][0];   // [128 i][128 j] bf16, XOR-swizzled

        // ---- copy 0: E-hi ----
        #pragma unroll
        for (int m = 0; m < 4; m++) {
            const int row = wr * 64 + m * 16 + l15;
            #pragma unroll
            for (int n = 0; n < 4; n++) {
                const int bc = (wc * 128 + n * 32 + l4 * 8) ^ ((row & 7) << 4);
                uint2 w;
                w.x = (unsigned)f2bf(acc[m][n][0]) | ((unsigned)f2bf(acc[m][n][1]) << 16);
                w.y = (unsigned)f2bf(acc[m][n][2]) | ((unsigned)f2bf(acc[m][n][3]) << 16);
                *(uint2*)(sE + row * 256 + bc) = w;
            }
        }
        #pragma unroll
        for (int m = 0; m < 4; m++) {
            const int row = wr * 64 + m * 16 + l15;
            #pragma unroll
            for (int kk = 0; kk < 2; kk++) {
                const int bc = ((wc * 2 + kk) * 64 + l4 * 16) ^ ((row & 7) << 4);
                short8 ef = *(const short8*)(sE + row * 256 + bc);
                #pragma unroll
                for (int cb = 0; cb < 2; cb++)
                    acc_cs[m][cb] = __builtin_amdgcn_mfma_f32_16x16x32_bf16(
                        ef, hf[kk][cb], acc_cs[m][cb], 0, 0, 0);
            }
        }
        // ---- copy 1: E-lo (recomputed, same LDS region) ----
        #pragma unroll
        for (int m = 0; m < 4; m++) {
            const int row = wr * 64 + m * 16 + l15;
            #pragma unroll
            for (int n = 0; n < 4; n++) {
                const int bc = (wc * 128 + n * 32 + l4 * 8) ^ ((row & 7) << 4);
                unsigned short lb[4];
                #pragma unroll
                for (int q = 0; q < 4; q++) {
                    float e = acc[m][n][q];
                    lb[q] = f2bf(e - bf2f(f2bf(e)));
                }
                uint2 w;
                w.x = (unsigned)lb[0] | ((unsigned)lb[1] << 16);
                w.y = (unsigned)lb[2] | ((unsigned)lb[3] << 16);
                *(uint2*)(sE + row * 256 + bc) = w;
            }
        }
        #pragma unroll
        for (int m = 0; m < 4; m++) {
            const int row = wr * 64 + m * 16 + l15;
            #pragma unroll
            for (int kk = 0; kk < 2; kk++) {
                const int bc = ((wc * 2 + kk) * 64 + l4 * 16) ^ ((row & 7) << 4);
                short8 ef = *(const short8*)(sE + row * 256 + bc);
                #pragma unroll
                for (int cb = 0; cb < 2; cb++)
                    acc_cs[m][cb] = __builtin_amdgcn_mfma_f32_16x16x32_bf16(
                        ef, hf[kk][cb], acc_cs[m][cb], 0, 0, 0);
            }
        }
        __syncthreads();   // drains next-tile prefetch; protects sE/slab
    }

    // ---- cross-wave (wc) reduce of class sums, write partials ----
    float* scls2 = (float*)&sbuf[0][0][0];   // [128][32] f32 (buf[0] dead)
    if (wc == 1) {
        #pragma unroll
        for (int m = 0; m < 4; m++)
            #pragma unroll
            for (int cb = 0; cb < 2; cb++)
                #pragma unroll
                for (int q = 0; q < 4; q++)
                    scls2[(wr * 64 + m * 16 + l4 * 4 + q) * NCLS + cb * 16 + l15] =
                        acc_cs[m][cb][q];
    }
    __syncthreads();
    float* pc = pcls + (size_t)swz * 128 * NCLS;
    if (wc == 0) {
        #pragma unroll
        for (int m = 0; m < 4; m++)
            #pragma unroll
            for (int cb = 0; cb < 2; cb++)
                #pragma unroll
                for (int q = 0; q < 4; q++) {
                    int iL = wr * 64 + m * 16 + l4 * 4 + q;
                    int c  = cb * 16 + l15;
                    pc[iL * NCLS + c] = acc_cs[m][cb][q] + scls2[iL * NCLS + c];
                }
    }
    if (t < 128) ppos[(size_t)swz * 128 + t] = spos[t];
}

// ---------------- kernel 4: per-anchor loss (8 lanes per anchor) ----------------
__global__ void reduce_kernel(const float* __restrict__ pcls, const float* __restrict__ ppos,
                              const int* __restrict__ counts, const int* __restrict__ labels,
                              float* __restrict__ loss_i, float* __restrict__ validf) {
    int tid = blockIdx.x * blockDim.x + threadIdx.x;
    int i  = tid >> 3;
    int cq = tid & 7;
    if (i >= B_SZ) return;
    int itile = i >> 7, ilocal = i & 127;

    f32x4 cs = (f32x4){0.f, 0.f, 0.f, 0.f};
    for (int ch = 0; ch < NCHUNK; ch++) {
        const float* p = pcls + ((size_t)(itile * NCHUNK + ch) * 128 + ilocal) * NCLS + cq * 4;
        f32x4 v = *(const f32x4*)p;
        cs = cs + v;
    }
    int labi = labels[i];
    float dpart = 0.0f;
    #pragma unroll
    for (int e = 0; e < 4; e++) {
        int c = cq * 4 + e;
        int cnt = counts[c] - (c == labi ? 1 : 0);
        if (cnt > 0) dpart += cs[e] / (float)cnt;
    }
    #pragma unroll
    for (int off = 1; off < 8; off <<= 1) dpart += __shfl_xor(dpart, off, 64);

    if (cq == 0) {
        float psum = 0.0f;
        for (int ch = 0; ch < NCHUNK; ch++)
            psum += ppos[(size_t)(itile * NCHUNK + ch) * 128 + ilocal];
        int P = counts[labi] - 1;
        bool valid = P > 0;
        float li = 0.0f;
        if (valid) li = logf(fmaxf(dpart, 1e-30f)) - psum / (float)max(P, 1);
        loss_i[i] = li;
        validf[i] = valid ? 1.0f : 0.0f;
    }
}

// ---------------- kernel 5: deterministic final reduction ----------------
__global__ void final_kernel(const float* __restrict__ loss_i, const float* __restrict__ validf,
                             float* __restrict__ out) {
    __shared__ float ssum[256];
    __shared__ float scnt[256];
    int t = threadIdx.x;
    float s = 0.0f, c = 0.0f;
    for (int i = t; i < B_SZ; i += 256) { s += loss_i[i]; c += validf[i]; }
    ssum[t] = s; scnt[t] = c;
    __syncthreads();
    #pragma unroll
    for (int off = 128; off > 0; off >>= 1) {
        if (t < off) { ssum[t] += ssum[t + off]; scnt[t] += scnt[t + off]; }
        __syncthreads();
    }
    if (t == 0) out[0] = (scnt[0] > 0.0f) ? ssum[0] / scnt[0] : 0.0f;
}

// ---------------- launch ----------------
extern "C" void kernel_launch(void* const* d_in, const int* in_sizes, int n_in,
                              void* d_out, int out_size, void* d_ws, size_t ws_size,
                              hipStream_t stream) {
    const float* feat   = (const float*)d_in[0];
    const int*   labels = (const int*)d_in[1];
    float*       out    = (float*)d_out;

    char* ws = (char*)d_ws;
    size_t off = 0;
    auto alloc = [&](size_t bytes) -> void* {
        void* p = ws + off;
        off = (off + bytes + 255) & ~(size_t)255;
        return p;
    };

    unsigned short* Aext = (unsigned short*)alloc((size_t)B_SZ * KE * 2);
    unsigned short* Bext = (unsigned short*)alloc((size_t)B_SZ * KE * 2);
    int*   counts = (int*)alloc((size_t)NCLS * 4);
    float* loss_i = (float*)alloc((size_t)B_SZ * 4);
    float* validf = (float*)alloc((size_t)B_SZ * 4);
    float* ppos   = (float*)alloc((size_t)64 * NCHUNK * 128 * 4);
    float* pcls   = (float*)alloc((size_t)64 * NCHUNK * 128 * NCLS * 4);

    prep_kernel<<<B_SZ / 4, 256, 0, stream>>>(feat, Aext, Bext);
    count_kernel<<<1, 256, 0, stream>>>(labels, counts);
    sim_kernel<<<64 * NCHUNK, 256, 0, stream>>>(Aext, Bext, labels, pcls, ppos);
    reduce_kernel<<<B_SZ * 8 / 256, 256, 0, stream>>>(pcls, ppos, counts, labels, loss_i, validf);
    final_kernel<<<1, 256, 0, stream>>>(loss_i, validf, out);
}

// Round 5
// 213.663 us; speedup vs baseline: 2.5940x; 1.2179x over previous
//
#include <hip/hip_runtime.h>
#include <math.h>

#define B_SZ  8192
#define KD    256
#define NCLS  32
#define NCHUNK 8          // j-chunks per i-row of tiles
#define JTPC   4          // 256-wide j-tiles per block
#define NJT    32         // total 256-wide j-tiles
#define SQRT_INVT 3.16227766016838f   // sqrt(10): fold 1/T into normalized rows

typedef __attribute__((ext_vector_type(8))) short short8;
typedef __attribute__((ext_vector_type(4))) float f32x4;

static __device__ __forceinline__ unsigned short f2bf(float f) {
    unsigned u = __float_as_uint(f);
    return (unsigned short)((u + 0x7FFF + ((u >> 16) & 1)) >> 16);   // RNE
}
static __device__ __forceinline__ float bf2f(unsigned short h) {
    return __uint_as_float((unsigned)h << 16);
}

// ---------------- kernel 1: normalize+scale rows, emit combined [hi(256)|lo(256)] bf16 ----------------
__global__ void prep_kernel(const float* __restrict__ feat, unsigned short* __restrict__ Fhl) {
    int row  = blockIdx.x * 4 + (threadIdx.x >> 6);
    int lane = threadIdx.x & 63;
    const float4 v = ((const float4*)(feat + (size_t)row * KD))[lane];
    float s = v.x * v.x + v.y * v.y + v.z * v.z + v.w * v.w;
    #pragma unroll
    for (int off = 1; off < 64; off <<= 1) s += __shfl_xor(s, off, 64);
    float rn = rsqrtf(s) * SQRT_INVT;
    float fn[4] = {v.x * rn, v.y * rn, v.z * rn, v.w * rn};
    ushort4 hi, lo;
    unsigned short* hp = (unsigned short*)&hi;
    unsigned short* lp = (unsigned short*)&lo;
    #pragma unroll
    for (int e = 0; e < 4; e++) {
        unsigned short h = f2bf(fn[e]);
        hp[e] = h;
        lp[e] = f2bf(fn[e] - bf2f(h));
    }
    ((ushort4*)(Fhl + (size_t)row * 512))[lane]      = hi;   // cols 0..255  = hi
    ((ushort4*)(Fhl + (size_t)row * 512 + 256))[lane] = lo;  // cols 256..511 = lo
}

// ---------------- kernel 2: global per-class counts ----------------
__global__ void count_kernel(const int* __restrict__ labels, int* __restrict__ counts) {
    __shared__ int sc[NCLS];
    int t = threadIdx.x;
    if (t < NCLS) sc[t] = 0;
    __syncthreads();
    for (int i = t; i < B_SZ; i += 256) atomicAdd(&sc[labels[i]], 1);
    __syncthreads();
    if (t < NCLS) counts[t] = sc[t];
}

// ---------------- kernel 3: 256x256-tile sim GEMM (shared hi/lo staging) + MFMA class reduce ----------------
// 256 blocks (1/CU), 512 threads = 8 waves in 2(row)x4(col); wave owns 128x64 of C.
// Per BK=32 round: stage Ahl[256][64] + Bhl[256][64] (32KB each), 3 products x 32 frags = 96 MFMA/wave.
__global__ __launch_bounds__(512, 2) void sim_kernel(
    const unsigned short* __restrict__ Fhl, const int* __restrict__ labels,
    float* __restrict__ pcls, float* __restrict__ ppos)
{
    __shared__ __align__(16) unsigned short sbuf[2][2][256 * 64];  // 128KB: [buf][A/B]
    __shared__ int   slab[256];
    __shared__ float spos[256];

    const int bid = blockIdx.x;
    const int swz = (bid & 7) * 32 + (bid >> 3);   // bijective XCD swizzle (256 % 8 == 0)
    const int itile = swz >> 3;                    // swz / NCHUNK
    const int jc    = swz & 7;                     // swz % NCHUNK
    const int i0    = itile * 256;

    const int t    = threadIdx.x;
    const int wave = t >> 6;
    const int lane = t & 63;
    const int wr   = wave >> 2;      // 0..1 -> 128-row half
    const int wc   = wave & 3;       // 0..3 -> 64-col quarter
    const int l15  = lane & 15;
    const int l4   = lane >> 4;

    if (t < 256) spos[t] = 0.0f;

    int labi[8];
    #pragma unroll
    for (int m = 0; m < 8; m++) labi[m] = labels[i0 + wr * 128 + m * 16 + l15];

    const int rT = t >> 3;    // row-within-64 staged per issue
    const int s8 = t & 7;     // physical 16B slot

    auto STAGE = [&](int buf, int j0s, int kc) {
        #pragma unroll
        for (int a = 0; a < 4; ++a) {
            int r  = a * 64 + rT;
            int sl = s8 ^ (r & 7);                      // logical slot (involution)
            int col = kc + (sl & 3) * 8 + ((sl & 4) << 6);  // hi slots 0-3, lo slots 4-7 (+256)
            const unsigned short* gA = Fhl + (size_t)(i0 + r) * 512 + col;
            char* lA = (char*)&sbuf[buf][0][0] + a * 8192 + wave * 1024;
            __builtin_amdgcn_global_load_lds(
                (const __attribute__((address_space(1))) void*)gA,
                (__attribute__((address_space(3))) void*)lA, 16, 0, 0);
            const unsigned short* gB = Fhl + (size_t)(j0s + r) * 512 + col;
            char* lB = (char*)&sbuf[buf][1][0] + a * 8192 + wave * 1024;
            __builtin_amdgcn_global_load_lds(
                (const __attribute__((address_space(1))) void*)gB,
                (__attribute__((address_space(3))) void*)lB, 16, 0, 0);
        }
    };

    #pragma unroll 1
    for (int jt = jc * JTPC; jt < (jc + 1) * JTPC; ++jt) {
        const int j0 = jt * 256;
        if (t < 256) slab[t] = labels[j0 + t];

        f32x4 acc[8][4];
        #pragma unroll
        for (int m = 0; m < 8; m++)
            #pragma unroll
            for (int n = 0; n < 4; n++)
                acc[m][n] = (f32x4){0.f, 0.f, 0.f, 0.f};

        STAGE(0, j0, 0);
        __syncthreads();

        // ---- 2-phase pipelined K-loop: 8 rounds of BK=32, 3 products per fragment ----
        #pragma unroll 1
        for (int ks = 0; ks < 8; ++ks) {
            if (ks < 7) STAGE((ks + 1) & 1, j0, (ks + 1) * 32);
            const unsigned short* pA = &sbuf[ks & 1][0][0];
            const unsigned short* pB = &sbuf[ks & 1][1][0];
            short8 bfh[4], bfl[4];
            #pragma unroll
            for (int n = 0; n < 4; ++n) {
                int r = wc * 64 + n * 16 + l15;
                bfh[n] = *(const short8*)&pB[r * 64 + ((l4 ^ (r & 7)) * 8)];
                bfl[n] = *(const short8*)&pB[r * 64 + (((4 + l4) ^ (r & 7)) * 8)];
            }
            #pragma unroll
            for (int m = 0; m < 8; ++m) {
                int r = wr * 128 + m * 16 + l15;
                short8 ah = *(const short8*)&pA[r * 64 + ((l4 ^ (r & 7)) * 8)];
                short8 al = *(const short8*)&pA[r * 64 + (((4 + l4) ^ (r & 7)) * 8)];
                #pragma unroll
                for (int n = 0; n < 4; ++n) {
                    // swapped operands: q indexes j. products: BhAh + BhAl + BlAh
                    acc[m][n] = __builtin_amdgcn_mfma_f32_16x16x32_bf16(bfh[n], ah, acc[m][n], 0, 0, 0);
                    acc[m][n] = __builtin_amdgcn_mfma_f32_16x16x32_bf16(bfh[n], al, acc[m][n], 0, 0, 0);
                    acc[m][n] = __builtin_amdgcn_mfma_f32_16x16x32_bf16(bfl[n], ah, acc[m][n], 0, 0, 0);
                }
            }
            __syncthreads();   // drains next stage; swaps buffers
        }

        // ---- epilogue: sim -> spos (rare atomics) + E=exp ----
        #pragma unroll
        for (int m = 0; m < 8; m++) {
            const int il = wr * 128 + m * 16 + l15;
            const int ig = i0 + il;
            #pragma unroll
            for (int n = 0; n < 4; n++) {
                const int jb = wc * 64 + n * 16 + l4 * 4;
                int4 lj = *(const int4*)&slab[jb];
                const int* ljp = (const int*)&lj;
                #pragma unroll
                for (int q = 0; q < 4; q++) {
                    const int jg = j0 + jb + q;
                    float sim = acc[m][n][q];            // already scaled by 1/T
                    bool self = (ig == jg);
                    if (!self && ljp[q] == labi[m]) atomicAdd(&spos[il], sim);
                    acc[m][n][q] = self ? 0.0f : __expf(sim);
                }
            }
        }

        // one-hot B-fragments over this wave's 64 j-cols (2 K=32 slices)
        short8 hf[2][2];
        #pragma unroll
        for (int kk = 0; kk < 2; kk++) {
            const int jb = wc * 64 + kk * 32 + l4 * 8;
            int4 lv0 = *(const int4*)&slab[jb];
            int4 lv1 = *(const int4*)&slab[jb + 4];
            int lv[8] = {lv0.x, lv0.y, lv0.z, lv0.w, lv1.x, lv1.y, lv1.z, lv1.w};
            #pragma unroll
            for (int cb = 0; cb < 2; cb++) {
                short8 h;
                #pragma unroll
                for (int e = 0; e < 8; e++)
                    h[e] = (lv[e] == cb * 16 + l15) ? (short)0x3F80 : (short)0;
                hf[kk][cb] = h;
            }
        }

        f32x4 acc_cs[8][2];
        #pragma unroll
        for (int m = 0; m < 8; m++)
            #pragma unroll
            for (int cb = 0; cb < 2; cb++)
                acc_cs[m][cb] = (f32x4){0.f, 0.f, 0.f, 0.f};

        char* sE = (char*)&sbuf[0][0][0];   // 128KB: [256 i][256 j] bf16, XOR-swizzled rows

        // copy 0: E-hi -> CS MFMA; copy 1: E-lo -> CS MFMA (same region, wave-private)
        #pragma unroll
        for (int copy = 0; copy < 2; copy++) {
            #pragma unroll
            for (int m = 0; m < 8; m++) {
                const int row = wr * 128 + m * 16 + l15;
                #pragma unroll
                for (int n = 0; n < 4; n++) {
                    const int bc = (wc * 128 + n * 32 + l4 * 8) ^ ((row & 7) << 4);
                    unsigned short b[4];
                    #pragma unroll
                    for (int q = 0; q < 4; q++) {
                        float e = acc[m][n][q];
                        unsigned short h = f2bf(e);
                        b[q] = copy == 0 ? h : f2bf(e - bf2f(h));
                    }
                    uint2 w;
                    w.x = (unsigned)b[0] | ((unsigned)b[1] << 16);
                    w.y = (unsigned)b[2] | ((unsigned)b[3] << 16);
                    *(uint2*)(sE + (size_t)row * 512 + bc) = w;
                }
            }
            #pragma unroll
            for (int m = 0; m < 8; m++) {
                const int row = wr * 128 + m * 16 + l15;
                #pragma unroll
                for (int kk = 0; kk < 2; kk++) {
                    const int bc = (wc * 128 + kk * 64 + l4 * 16) ^ ((row & 7) << 4);
                    short8 ef = *(const short8*)(sE + (size_t)row * 512 + bc);
                    #pragma unroll
                    for (int cb = 0; cb < 2; cb++)
                        acc_cs[m][cb] = __builtin_amdgcn_mfma_f32_16x16x32_bf16(
                            ef, hf[kk][cb], acc_cs[m][cb], 0, 0, 0);
                }
            }
        }

        // ---- deterministic cross-wave (wc) reduce via LDS, write per-tile partials ----
        __syncthreads();                       // all CS reads done; sbuf reusable
        float* scr = (float*)&sbuf[0][0][0];   // [6][128][33] f32 = 101KB
        if (wc > 0) {
            const int idx = (wc - 1) * 2 + wr;
            #pragma unroll
            for (int m = 0; m < 8; m++)
                #pragma unroll
                for (int cb = 0; cb < 2; cb++)
                    #pragma unroll
                    for (int q = 0; q < 4; q++)
                        scr[((size_t)idx * 128 + m * 16 + l4 * 4 + q) * 33 + cb * 16 + l15] =
                            acc_cs[m][cb][q];
        }
        __syncthreads();
        if (wc == 0) {
            float* pc = pcls + (size_t)(itile * NJT + jt) * 256 * NCLS;
            #pragma unroll
            for (int m = 0; m < 8; m++)
                #pragma unroll
                for (int cb = 0; cb < 2; cb++)
                    #pragma unroll
                    for (int q = 0; q < 4; q++) {
                        const int r128 = m * 16 + l4 * 4 + q;
                        const int c    = cb * 16 + l15;
                        float v = acc_cs[m][cb][q];
                        #pragma unroll
                        for (int k = 0; k < 3; k++)
                            v += scr[((size_t)(k * 2 + wr) * 128 + r128) * 33 + c];
                        pc[(wr * 128 + r128) * NCLS + c] = v;
                    }
        }
        __syncthreads();   // scr consumed before next tile's STAGE overwrites
    }

    if (t < 256) ppos[(size_t)swz * 256 + t] = spos[t];
}

// ---------------- kernel 4: per-anchor loss (8 lanes per anchor) ----------------
__global__ void reduce_kernel(const float* __restrict__ pcls, const float* __restrict__ ppos,
                              const int* __restrict__ counts, const int* __restrict__ labels,
                              float* __restrict__ loss_i, float* __restrict__ validf) {
    int tid = blockIdx.x * blockDim.x + threadIdx.x;
    int i  = tid >> 3;
    int cq = tid & 7;
    if (i >= B_SZ) return;
    int itile = i >> 8, ilocal = i & 255;

    f32x4 cs = (f32x4){0.f, 0.f, 0.f, 0.f};
    for (int ch = 0; ch < NJT; ch++) {
        const float* p = pcls + ((size_t)(itile * NJT + ch) * 256 + ilocal) * NCLS + cq * 4;
        f32x4 v = *(const f32x4*)p;
        cs = cs + v;
    }
    int labi = labels[i];
    float dpart = 0.0f;
    #pragma unroll
    for (int e = 0; e < 4; e++) {
        int c = cq * 4 + e;
        int cnt = counts[c] - (c == labi ? 1 : 0);
        if (cnt > 0) dpart += cs[e] / (float)cnt;
    }
    #pragma unroll
    for (int off = 1; off < 8; off <<= 1) dpart += __shfl_xor(dpart, off, 64);

    if (cq == 0) {
        float psum = 0.0f;
        for (int ch = 0; ch < NCHUNK; ch++)
            psum += ppos[(size_t)(itile * NCHUNK + ch) * 256 + ilocal];
        int P = counts[labi] - 1;
        bool valid = P > 0;
        float li = 0.0f;
        if (valid) li = logf(fmaxf(dpart, 1e-30f)) - psum / (float)max(P, 1);
        loss_i[i] = li;
        validf[i] = valid ? 1.0f : 0.0f;
    }
}

// ---------------- kernel 5: deterministic final reduction ----------------
__global__ void final_kernel(const float* __restrict__ loss_i, const float* __restrict__ validf,
                             float* __restrict__ out) {
    __shared__ float ssum[256];
    __shared__ float scnt[256];
    int t = threadIdx.x;
    float s = 0.0f, c = 0.0f;
    for (int i = t; i < B_SZ; i += 256) { s += loss_i[i]; c += validf[i]; }
    ssum[t] = s; scnt[t] = c;
    __syncthreads();
    #pragma unroll
    for (int off = 128; off > 0; off >>= 1) {
        if (t < off) { ssum[t] += ssum[t + off]; scnt[t] += scnt[t + off]; }
        __syncthreads();
    }
    if (t == 0) out[0] = (scnt[0] > 0.0f) ? ssum[0] / scnt[0] : 0.0f;
}

// ---------------- launch ----------------
extern "C" void kernel_launch(void* const* d_in, const int* in_sizes, int n_in,
                              void* d_out, int out_size, void* d_ws, size_t ws_size,
                              hipStream_t stream) {
    const float* feat   = (const float*)d_in[0];
    const int*   labels = (const int*)d_in[1];
    float*       out    = (float*)d_out;

    char* ws = (char*)d_ws;
    size_t off = 0;
    auto alloc = [&](size_t bytes) -> void* {
        void* p = ws + off;
        off = (off + bytes + 255) & ~(size_t)255;
        return p;
    };

    unsigned short* Fhl = (unsigned short*)alloc((size_t)B_SZ * 512 * 2);     // 8.4MB
    int*   counts = (int*)alloc((size_t)NCLS * 4);
    float* loss_i = (float*)alloc((size_t)B_SZ * 4);
    float* validf = (float*)alloc((size_t)B_SZ * 4);
    float* ppos   = (float*)alloc((size_t)256 * 256 * 4);                     // 256KB
    float* pcls   = (float*)alloc((size_t)32 * NJT * 256 * NCLS * 4);         // 32MB

    prep_kernel<<<B_SZ / 4, 256, 0, stream>>>(feat, Fhl);
    count_kernel<<<1, 256, 0, stream>>>(labels, counts);
    sim_kernel<<<256, 512, 0, stream>>>(Fhl, labels, pcls, ppos);
    reduce_kernel<<<B_SZ * 8 / 256, 256, 0, stream>>>(pcls, ppos, counts, labels, loss_i, validf);
    final_kernel<<<1, 256, 0, stream>>>(loss_i, validf, out);
}